// Round 3
// baseline (2994.460 us; speedup 1.0000x reference)
//
#include <hip/hip_runtime.h>
#include <hip/hip_bf16.h>

// Problem: x[32,128,56,56] fp32; W[8,128,128,3,3]; out = BN(sum_i conv3x3(roll(x,s_i), W_i))
// SHIFTS (dx,dy): dx applied to H axis, dy to W axis; roll[h,w] = x[(h-dx)%56,(w-dy)%56]
//
// Strategy: collapse the 8 shifted 3x3 convs into one circular 5x5 conv with
// weights V[o,c,a,b] = sum_i W[i,o,c,a+1+dx_i,b+1+dy_i]  (a,b in [-2..2]).
// This is exact except at border pixels where the zero-pad mask kills taps;
// a border-fix kernel subtracts exactly those circularly-included bad taps.

static_assert(sizeof(float) == 4, "");

__global__ void build_V_kernel(const float* __restrict__ W, float* __restrict__ V) {
    int idx = blockIdx.x * 256 + threadIdx.x;
    const int total = 128 * 128 * 25;
    if (idx >= total) return;
    int tap = idx % 25;
    int oc  = idx / 25;
    int b = tap % 5, a = tap / 5;          // a,b in [0,5), offset = a-2, b-2
    int c = oc % 128, o = oc / 128;
    const int dxs[8] = {-1, 0, 1, -1, 1, -1, 0, 1};
    const int dys[8] = {-1, -1, -1, 0, 0, 1, 1, 1};
    float s = 0.f;
#pragma unroll
    for (int i = 0; i < 8; ++i) {
        int kh = a - 1 + dxs[i];           // kh = (a-2) + 1 + dx
        int kw = b - 1 + dys[i];
        if (kh >= 0 && kh < 3 && kw >= 0 && kw < 3)
            s += W[(((size_t)i * 128 + o) * 128 + c) * 9 + kh * 3 + kw];
    }
    V[idx] = s;
}

// Main conv: circular 5x5 with V, all pixels.
// Block: 448 threads; tile = 28 rows x 56 cols x 16 o. Thread: hl = t/64 (7 layers),
// wsl = t%64 (56 active); computes rows hl + 7p (p=0..3) => 4 px x 16 o = 64 acc.
// c processed in chunks of 4 staged in LDS (32 halo rows x 60 halo cols).
#define CCHUNK 4
__global__ __launch_bounds__(448) void conv_main_kernel(
    const float* __restrict__ x, const float* __restrict__ V, float* __restrict__ out) {
    __shared__ float xs[CCHUNK][32][64];
    __shared__ float vs[16][CCHUNK][25];
    const int n  = blockIdx.x;
    const int h0 = blockIdx.y * 28;
    const int o0 = blockIdx.z * 16;
    const int t  = threadIdx.x;
    const int hl  = t >> 6;                // 0..6
    const int wsl = t & 63;                // 0..63, active < 56
    const int wc  = wsl < 55 ? wsl : 55;   // clamp for idle lanes (reads stay in-bounds)

    float acc[4][16];
#pragma unroll
    for (int p = 0; p < 4; ++p)
#pragma unroll
        for (int j = 0; j < 16; ++j) acc[p][j] = 0.f;

#pragma unroll 1
    for (int ch = 0; ch < 128 / CCHUNK; ++ch) {
        const int c0 = ch * CCHUNK;
        // stage x tile: rows (h0-2+r)%56, cols (j-2)%56
        for (int i = t; i < CCHUNK * 32 * 60; i += 448) {
            int j  = i % 60;
            int r  = (i / 60) % 32;
            int cc = i / (60 * 32);
            int gr = h0 - 2 + r; gr += (gr < 0) ? 56 : 0; gr -= (gr >= 56) ? 56 : 0;
            int gc = j - 2;      gc += (gc < 0) ? 56 : 0; gc -= (gc >= 56) ? 56 : 0;
            xs[cc][r][j] = x[((size_t)(n * 128 + c0 + cc) * 56 + gr) * 56 + gc];
        }
        // stage V chunk
        for (int i = t; i < 16 * CCHUNK * 25; i += 448) {
            int tap = i % 25;
            int cc  = (i / 25) % CCHUNK;
            int ot  = i / (25 * CCHUNK);
            vs[ot][cc][tap] = V[((size_t)(o0 + ot) * 128 + (c0 + cc)) * 25 + tap];
        }
        __syncthreads();

#pragma unroll 1
        for (int cc = 0; cc < CCHUNK; ++cc) {
#pragma unroll 1
            for (int a = 0; a < 5; ++a) {
#pragma unroll
                for (int b = 0; b < 5; ++b) {
                    float x0 = xs[cc][hl +      a][wc + b];
                    float x1 = xs[cc][hl +  7 + a][wc + b];
                    float x2 = xs[cc][hl + 14 + a][wc + b];
                    float x3 = xs[cc][hl + 21 + a][wc + b];
#pragma unroll
                    for (int j = 0; j < 16; ++j) {
                        float vv = vs[j][cc][a * 5 + b];
                        acc[0][j] = fmaf(vv, x0, acc[0][j]);
                        acc[1][j] = fmaf(vv, x1, acc[1][j]);
                        acc[2][j] = fmaf(vv, x2, acc[2][j]);
                        acc[3][j] = fmaf(vv, x3, acc[3][j]);
                    }
                }
            }
        }
        __syncthreads();
    }

    if (wsl < 56) {
#pragma unroll
        for (int p = 0; p < 4; ++p) {
            int h = h0 + hl + 7 * p;
#pragma unroll
            for (int j = 0; j < 16; ++j) {
                out[((size_t)(n * 128 + o0 + j) * 56 + h) * 56 + wsl] = acc[p][j];
            }
        }
    }
}

// Border fix: subtract taps the zero-pad mask excludes but the circular conv included.
// e=0: h=0  (bad kh=0, all kw)      e=1: h=55 (bad kh=2, all kw)
// e=2: w=0  (bad kw=0, valid kh)    e=3: w=55 (bad kw=2, valid kh)
// (corners get one correction from each family; tap sets are disjoint => atomicAdd)
__global__ __launch_bounds__(256) void border_fix_kernel(
    const float* __restrict__ x, const float* __restrict__ W, float* __restrict__ out) {
    const int n = blockIdx.x, e = blockIdx.y, og = blockIdx.z;
    const int t = threadIdx.x;
    const int px  = t & 63;
    const int grp = t >> 6;
    if (px >= 56) return;
    const int obase = og * 32 + grp * 8;
    const int dxs[8] = {-1, 0, 1, -1, 1, -1, 0, 1};
    const int dys[8] = {-1, -1, -1, 0, 0, 1, 1, 1};
    int h, w;
    if (e == 0)      { h = 0;  w = px; }
    else if (e == 1) { h = 55; w = px; }
    else if (e == 2) { h = px; w = 0;  }
    else             { h = px; w = 55; }
    float acc[8] = {0.f, 0.f, 0.f, 0.f, 0.f, 0.f, 0.f, 0.f};

#pragma unroll 1
    for (int c = 0; c < 128; ++c) {
        const float* xc = x + ((size_t)(n * 128 + c)) * 3136;
        if (e < 2) {
            const int kh = (e == 0) ? 0 : 2;
            const int hh = h + kh - 1;     // -1 or 56
#pragma unroll
            for (int kw = 0; kw < 3; ++kw) {
                const int ww = w + kw - 1;
#pragma unroll
                for (int i = 0; i < 8; ++i) {
                    int sr = hh - dxs[i]; sr += (sr < 0) ? 56 : 0; sr -= (sr >= 56) ? 56 : 0;
                    int sc = ww - dys[i]; sc += (sc < 0) ? 56 : 0; sc -= (sc >= 56) ? 56 : 0;
                    float xv = xc[sr * 56 + sc];
#pragma unroll
                    for (int j = 0; j < 8; ++j)
                        acc[j] = fmaf(W[(((size_t)i * 128 + obase + j) * 128 + c) * 9 + kh * 3 + kw], xv, acc[j]);
                }
            }
        } else {
            const int kw = (e == 2) ? 0 : 2;
            const int ww = w + kw - 1;     // -1 or 56
#pragma unroll
            for (int kh = 0; kh < 3; ++kh) {
                const int hh = h + kh - 1;
                if (hh < 0 || hh >= 56) continue;   // those taps belong to e<2 kernels
#pragma unroll
                for (int i = 0; i < 8; ++i) {
                    int sr = hh - dxs[i]; sr += (sr < 0) ? 56 : 0; sr -= (sr >= 56) ? 56 : 0;
                    int sc = ww - dys[i]; sc += (sc < 0) ? 56 : 0; sc -= (sc >= 56) ? 56 : 0;
                    float xv = xc[sr * 56 + sc];
#pragma unroll
                    for (int j = 0; j < 8; ++j)
                        acc[j] = fmaf(W[(((size_t)i * 128 + obase + j) * 128 + c) * 9 + kh * 3 + kw], xv, acc[j]);
                }
            }
        }
    }
#pragma unroll
    for (int j = 0; j < 8; ++j)
        atomicAdd(&out[((size_t)(n * 128 + obase + j)) * 3136 + h * 56 + w], -acc[j]);
}

// BN stats: one block per channel; sum & sumsq over 32*56*56 = 100352 elements.
__global__ __launch_bounds__(256) void bn_stats_kernel(
    const float* __restrict__ out, float* __restrict__ stats) {
    const int c = blockIdx.x;
    const int t = threadIdx.x;
    float s = 0.f, q = 0.f;
    for (int n = 0; n < 32; ++n) {
        const float* p = out + ((size_t)(n * 128 + c)) * 3136;
        for (int i = t; i < 3136; i += 256) {
            float v = p[i];
            s += v;
            q = fmaf(v, v, q);
        }
    }
    __shared__ float rs[256], rq[256];
    rs[t] = s; rq[t] = q;
    __syncthreads();
    for (int st = 128; st > 0; st >>= 1) {
        if (t < st) { rs[t] += rs[t + st]; rq[t] += rq[t + st]; }
        __syncthreads();
    }
    if (t == 0) {
        const float inv = 1.f / 100352.f;
        float mean = rs[0] * inv;
        float var  = rq[0] * inv - mean * mean;   // biased variance
        stats[c]       = mean;
        stats[128 + c] = rsqrtf(var + 1e-5f);
    }
}

__global__ __launch_bounds__(256) void bn_apply_kernel(
    float* __restrict__ out, const float* __restrict__ stats,
    const float* __restrict__ gamma, const float* __restrict__ beta) {
    const size_t total4 = (size_t)32 * 128 * 3136 / 4;   // 3,211,264
    size_t idx = (size_t)blockIdx.x * 256 + threadIdx.x;
    if (idx >= total4) return;
    int c = (int)((idx / 784) % 128);                    // 3136/4 = 784 float4 per (n,c) plane
    float m = stats[c];
    float g = gamma[c] * stats[128 + c];
    float bt = beta[c];
    float4* o4 = (float4*)out;
    float4 v = o4[idx];
    v.x = (v.x - m) * g + bt;
    v.y = (v.y - m) * g + bt;
    v.z = (v.z - m) * g + bt;
    v.w = (v.w - m) * g + bt;
    o4[idx] = v;
}

extern "C" void kernel_launch(void* const* d_in, const int* in_sizes, int n_in,
                              void* d_out, int out_size, void* d_ws, size_t ws_size,
                              hipStream_t stream) {
    const float* x     = (const float*)d_in[0];
    const float* W     = (const float*)d_in[1];
    const float* gamma = (const float*)d_in[2];
    const float* beta  = (const float*)d_in[3];
    float* out = (float*)d_out;

    float* V     = (float*)d_ws;             // 128*128*25 floats = 1.6 MB
    float* stats = V + 128 * 128 * 25;       // 256 floats (mean[128], rstd[128])

    build_V_kernel<<<(128 * 128 * 25 + 255) / 256, 256, 0, stream>>>(W, V);
    conv_main_kernel<<<dim3(32, 2, 8), 448, 0, stream>>>(x, V, out);
    border_fix_kernel<<<dim3(32, 4, 4), 256, 0, stream>>>(x, W, out);
    bn_stats_kernel<<<128, 256, 0, stream>>>(out, stats);
    bn_apply_kernel<<<(3211264 + 255) / 256, 256, 0, stream>>>(out, stats, gamma, beta);
}

// Round 5
// 505.957 us; speedup vs baseline: 5.9184x; 5.9184x over previous
//
#include <hip/hip_runtime.h>
#include <hip/hip_bf16.h>

// out = BN(sum_i conv3x3(roll(x, s_i), W_i)), x[32,128,56,56] fp32, W[8,128,128,3,3].
// Interior = circular 5x5 conv with collapsed weights V, computed as bf16 MFMA
// implicit GEMM (M=o 128, N=pixels, K=c*25taps=3200). Borders fixed exactly in
// fp32 via per-edge collapsed weights U + corner add-back Uc. BN stats fused
// into conv/border/corner epilogues as deterministic per-slot partials.

typedef __attribute__((ext_vector_type(8)))  short s16x8;   // 8 bf16 (4 VGPR)
typedef __attribute__((ext_vector_type(16))) float f32x16;  // MFMA 32x32 accum

__device__ __forceinline__ void gload16(const void* g, void* l) {
    __builtin_amdgcn_global_load_lds(
        (const __attribute__((address_space(1))) unsigned int*)g,
        (__attribute__((address_space(3))) unsigned int*)l, 16, 0, 0);
}

__device__ __forceinline__ unsigned short f2bf(float f) {
    __hip_bfloat16 h = __float2bfloat16(f);
    return *(unsigned short*)&h;
}

// ---------- prep 1: x[n][c][h][w] fp32 -> xb[n][h][w][c] bf16 ----------
__global__ __launch_bounds__(256) void transpose_kernel(
    const float* __restrict__ x, unsigned short* __restrict__ xb) {
    __shared__ float xt[128][57];
    const int h = blockIdx.x, n = blockIdx.y, t = threadIdx.x;
    for (int it = 0; it < 28; ++it) {
        int idx = it * 256 + t;                 // 7168 = 128c * 56w
        int c = idx / 56, w = idx % 56;
        xt[c][w] = x[(((size_t)n * 128 + c) * 56 + h) * 56 + w];
    }
    __syncthreads();
    for (int it = 0; it < 4; ++it) {
        int unit = it * 256 + t;                // 896 = 56w * 16cu
        if (unit < 896) {
            int w = unit >> 4, cu = unit & 15;
            unsigned short pk[8];
#pragma unroll
            for (int j = 0; j < 8; ++j) pk[j] = f2bf(xt[cu * 8 + j][w]);
            *(uint4*)(xb + ((((size_t)n * 56 + h) * 56 + w) * 128 + cu * 8)) = *(uint4*)pk;
        }
    }
}

// ---------- prep 2: W -> V(bf16) packed as 32x32x16 A-fragments ----------
// Ap layout: [chunk 8][tap 25][mo 4][lane 64][8 shorts]  (1KB per fragment)
__global__ __launch_bounds__(256) void vpack_kernel(
    const float* __restrict__ W, unsigned short* __restrict__ Ap) {
    int idx = blockIdx.x * 256 + threadIdx.x;   // 128*128*25 = 409600 exact
    int tap = idx % 25, oc = idx / 25, c = oc % 128, o = oc / 128;
    int a = tap / 5, b = tap % 5;
    const int dxs[8] = {-1, 0, 1, -1, 1, -1, 0, 1};
    const int dys[8] = {-1, -1, -1, 0, 0, 1, 1, 1};
    float s = 0.f;
#pragma unroll
    for (int i = 0; i < 8; ++i) {
        int kh = a - 1 + dxs[i];
        int kw = b - 1 + dys[i];
        if (kh >= 0 && kh < 3 && kw >= 0 && kw < 3)
            s += W[(((size_t)i * 128 + o) * 128 + c) * 9 + kh * 3 + kw];
    }
    int chunk = c >> 4, k = c & 15, ku = k >> 3, j = k & 7, mo = o >> 5;
    size_t off = ((((size_t)chunk * 25 + tap) * 4 + mo) * 64 + (ku * 32 + (o & 31))) * 8 + j;
    Ap[off] = f2bf(s);
}

// ---------- prep 3: per-edge collapsed border weights U[e][3r][5b][c][o] ----------
__global__ __launch_bounds__(256) void ubuild_kernel(
    const float* __restrict__ W, float* __restrict__ U) {
    int idx = blockIdx.x * 256 + threadIdx.x;   // 4*128*128 = 65536 exact
    int c = idx % 128, o = (idx / 128) % 128, e = idx / 16384;
    const int dxs[8] = {-1, 0, 1, -1, 1, -1, 0, 1};
    const int dys[8] = {-1, -1, -1, 0, 0, 1, 1, 1};
    float u[15];
#pragma unroll
    for (int k = 0; k < 15; ++k) u[k] = 0.f;
#pragma unroll
    for (int i = 0; i < 8; ++i) {
        if (e < 2) {
            int kh = (e == 0) ? 0 : 2;
            int hh = (e == 0) ? -1 : 56;
            int sr = (hh - dxs[i] + 56) % 56;
            int r = (e == 0) ? (sr == 54 ? 0 : sr == 55 ? 1 : 2)
                             : (sr == 55 ? 0 : sr == 0 ? 1 : 2);
#pragma unroll
            for (int kw = 0; kw < 3; ++kw) {
                int be = kw - 1 - dys[i] + 2;
                u[r * 5 + be] += W[(((size_t)i * 128 + o) * 128 + c) * 9 + kh * 3 + kw];
            }
        } else {
            int kw = (e == 2) ? 0 : 2;
            int ww = (e == 2) ? -1 : 56;
            int sc = (ww - dys[i] + 56) % 56;
            int r = (e == 2) ? (sc == 54 ? 0 : sc == 55 ? 1 : 2)
                             : (sc == 55 ? 0 : sc == 0 ? 1 : 2);
#pragma unroll
            for (int kh = 0; kh < 3; ++kh) {
                int al = kh - 1 - dxs[i] + 2;
                u[r * 5 + al] += W[(((size_t)i * 128 + o) * 128 + c) * 9 + kh * 3 + kw];
            }
        }
    }
#pragma unroll
    for (int k = 0; k < 15; ++k)
        U[(((size_t)e * 15 + k) * 128 + c) * 128 + o] = u[k];
}

// ---------- prep 4: corner add-back weights Uc[cr][9pos][c][o] ----------
// (e<2 kernels subtract all-kw at bad kh; e>=2 subtract all-kh at bad kw ->
//  the corner tap (bad kh AND bad kw) is subtracted twice; add it back once.)
__global__ __launch_bounds__(256) void ucbuild_kernel(
    const float* __restrict__ W, float* __restrict__ Uc) {
    int idx = blockIdx.x * 256 + threadIdx.x;   // 4*128*128
    int c = idx % 128, o = (idx / 128) % 128, cr = idx / 16384;
    int hC = (cr >> 1) ? 55 : 0, wC = (cr & 1) ? 55 : 0;
    int khb = hC ? 2 : 0, kwb = wC ? 2 : 0;
    const int dxs[8] = {-1, 0, 1, -1, 1, -1, 0, 1};
    const int dys[8] = {-1, -1, -1, 0, 0, 1, 1, 1};
    float v[9];
#pragma unroll
    for (int p = 0; p < 9; ++p) v[p] = 0.f;
#pragma unroll
    for (int i = 0; i < 8; ++i)
        v[(dxs[i] + 1) * 3 + (dys[i] + 1)] = W[(((size_t)i * 128 + o) * 128 + c) * 9 + khb * 3 + kwb];
#pragma unroll
    for (int p = 0; p < 9; ++p)
        Uc[(((size_t)cr * 9 + p) * 128 + c) * 128 + o] = v[p];
}

// ---------- main: circular 5x5 conv via MFMA implicit GEMM ----------
// grid (7 px-tiles of 512, 32 n), 512 thr = 8 waves = og(2:o-half) x pg(4:px-grp).
// Wave: M_rep=2 (o = og*64 + {0,32}) x N_rep=4 (px = p0+pg*128 + {0,32,64,96}).
// LDS: xs = x tile [15 rows][60 w][16 c] bf16 ; As = A-frags for chunk.
__global__ __launch_bounds__(512, 2) void conv_mfma(
    const unsigned short* __restrict__ xb, const unsigned short* __restrict__ Ap,
    float* __restrict__ out, float* __restrict__ P) {
    __shared__ __align__(16) unsigned short lds[69632];   // 139,264 B
    unsigned short* xs = lds;                    // 2048 units * 16B = 32,768 B
    unsigned short* As = lds + 16384;            // 6656 units * 16B = 106,496 B
    const int tile = blockIdx.x, n = blockIdx.y;
    const int p0 = tile * 512;
    const int t = threadIdx.x, wv = t >> 6, lane = t & 63;
    const int og = wv >> 2, pg = wv & 3;
    const int hstart = p0 / 56 - 2;

    int vB[4];
    bool fval[4];
#pragma unroll
    for (int nn = 0; nn < 4; ++nn) {
        int px = p0 + pg * 128 + nn * 32 + (lane & 31);
        fval[nn] = px < 3136;
        if (px > 3135) px = 3135;
        int h = px / 56, w = px % 56;
        vB[nn] = ((h - hstart - 2) * 60 + w) * 32 + (lane >> 5) * 16;   // bytes
    }
    f32x16 acc[2][4];
#pragma unroll
    for (int mm = 0; mm < 2; ++mm)
#pragma unroll
        for (int nn = 0; nn < 4; ++nn)
#pragma unroll
            for (int r = 0; r < 16; ++r) acc[mm][nn][r] = 0.f;

    const unsigned short* xbn = xb + (size_t)n * 401408;   // 56*56*128

#pragma unroll 1
    for (int ch = 0; ch < 8; ++ch) {
        // stage x tile (rows hstart..hstart+14 circular, w-halo +-2 circular)
#pragma unroll
        for (int it = 0; it < 4; ++it) {
            int unit = it * 512 + t;            // 0..2047 (>=1800 = padding rows)
            int ph = unit >> 1, u = unit & 1;
            int r = ph / 60, wc2 = ph % 60;
            int gh = ((hstart + r) % 56 + 56) % 56;
            int gw = wc2 - 2;
            gw += (gw < 0) ? 56 : 0;
            gw -= (gw >= 56) ? 56 : 0;
            gload16(xbn + (gh * 56 + gw) * 128 + ch * 16 + u * 8,
                    (char*)xs + (size_t)(it * 512 + wv * 64) * 16);
        }
        // stage A-frags for this chunk (all 25 taps x 4 mo), linear copy
        const unsigned short* apc = Ap + (size_t)ch * 51200;
#pragma unroll
        for (int it = 0; it < 13; ++it) {
            int unit = it * 512 + t;            // 0..6655 (>=6400 = padding)
            gload16(apc + (size_t)unit * 8,
                    (char*)As + (size_t)(it * 512 + wv * 64) * 16);
        }
        __syncthreads();

#pragma unroll
        for (int tap = 0; tap < 25; ++tap) {
            const int toff = ((tap / 5) * 60 + (tap % 5)) * 32;
            s16x8 a0 = *(const s16x8*)((const char*)As + (size_t)(tap * 4 + og * 2 + 0) * 1024 + lane * 16);
            s16x8 a1 = *(const s16x8*)((const char*)As + (size_t)(tap * 4 + og * 2 + 1) * 1024 + lane * 16);
            s16x8 b0 = *(const s16x8*)((const char*)xs + vB[0] + toff);
            s16x8 b1 = *(const s16x8*)((const char*)xs + vB[1] + toff);
            s16x8 b2 = *(const s16x8*)((const char*)xs + vB[2] + toff);
            s16x8 b3 = *(const s16x8*)((const char*)xs + vB[3] + toff);
            acc[0][0] = __builtin_amdgcn_mfma_f32_32x32x16_bf16(a0, b0, acc[0][0], 0, 0, 0);
            acc[1][0] = __builtin_amdgcn_mfma_f32_32x32x16_bf16(a1, b0, acc[1][0], 0, 0, 0);
            acc[0][1] = __builtin_amdgcn_mfma_f32_32x32x16_bf16(a0, b1, acc[0][1], 0, 0, 0);
            acc[1][1] = __builtin_amdgcn_mfma_f32_32x32x16_bf16(a1, b1, acc[1][1], 0, 0, 0);
            acc[0][2] = __builtin_amdgcn_mfma_f32_32x32x16_bf16(a0, b2, acc[0][2], 0, 0, 0);
            acc[1][2] = __builtin_amdgcn_mfma_f32_32x32x16_bf16(a1, b2, acc[1][2], 0, 0, 0);
            acc[0][3] = __builtin_amdgcn_mfma_f32_32x32x16_bf16(a0, b3, acc[0][3], 0, 0, 0);
            acc[1][3] = __builtin_amdgcn_mfma_f32_32x32x16_bf16(a1, b3, acc[1][3], 0, 0, 0);
        }
        __syncthreads();
    }

    // epilogue: store + per-channel partial (sum, sumsq) -> P[slot]
    const int slot = (n * 7 + tile) * 4 + pg;
#pragma unroll
    for (int mm = 0; mm < 2; ++mm) {
#pragma unroll
        for (int r = 0; r < 16; ++r) {
            int o = og * 64 + mm * 32 + (r & 3) + ((lane >> 5) << 2) + ((r >> 2) << 3);
            float s = 0.f, q = 0.f;
#pragma unroll
            for (int nn = 0; nn < 4; ++nn) {
                if (fval[nn]) {
                    float v = acc[mm][nn][r];
                    size_t oi = ((size_t)(n * 128 + o)) * 3136 + (p0 + pg * 128 + nn * 32 + (lane & 31));
                    out[oi] = v;
                    s += v;
                    q = fmaf(v, v, q);
                }
            }
#pragma unroll
            for (int off = 1; off < 32; off <<= 1) {
                s += __shfl_xor(s, off);
                q += __shfl_xor(q, off);
            }
            if ((lane & 31) == 0) {
                P[((size_t)slot * 2 + 0) * 128 + o] = s;
                P[((size_t)slot * 2 + 1) * 128 + o] = q;
            }
        }
    }
}

// ---------- border: subtract exact correction, track stats delta ----------
// grid (2 edges, 32 n, 2 o-halves) x 2 sequential launches (ebase 0 then 2):
// e=0/1 touch rows 0/55; e=2/3 touch cols 0/55. Corners are touched by one
// edge in EACH launch -> launches must be serialized (RMW, no atomics).
__global__ __launch_bounds__(256) void border_kernel(
    const float* __restrict__ x, const float* __restrict__ U,
    float* __restrict__ out, float* __restrict__ P, int ebase) {
    __shared__ float xsb[3][128][60];
    const int e = ebase + blockIdx.x, n = blockIdx.y, oh = blockIdx.z;
    const int t = threadIdx.x;
    int rows[3];
    if (e == 0 || e == 2) { rows[0] = 54; rows[1] = 55; rows[2] = 0; }
    else                  { rows[0] = 55; rows[1] = 0;  rows[2] = 1; }
    for (int it = 0; it < 90; ++it) {
        int idx = it * 256 + t;                 // 3*128*60 = 23040 exact
        int m = idx % 60, c = (idx / 60) % 128, r = idx / 7680;
        int g = m - 2;
        g += (g < 0) ? 56 : 0;
        g -= (g >= 56) ? 56 : 0;
        float v;
        if (e < 2) v = x[(((size_t)n * 128 + c) * 56 + rows[r]) * 56 + g];
        else       v = x[(((size_t)n * 128 + c) * 56 + g) * 56 + rows[r]];
        xsb[r][c][m] = v;
    }
    __syncthreads();
    const int o = oh * 64 + (t >> 2), q = t & 3;
    const int base = q * 14;
    float corr[14];
#pragma unroll
    for (int k = 0; k < 14; ++k) corr[k] = 0.f;
#pragma unroll 1
    for (int c = 0; c < 128; ++c) {
#pragma unroll
        for (int r = 0; r < 3; ++r) {
            float xl[18];
#pragma unroll
            for (int j = 0; j < 18; ++j) xl[j] = xsb[r][c][base + j];
#pragma unroll
            for (int be = 0; be < 5; ++be) {
                float u = U[(((size_t)e * 15 + r * 5 + be) * 128 + c) * 128 + o];
#pragma unroll
                for (int k = 0; k < 14; ++k) corr[k] = fmaf(u, xl[k + be], corr[k]);
            }
        }
    }
    float sd = 0.f, sq = 0.f;
#pragma unroll
    for (int k = 0; k < 14; ++k) {
        int ec = base + k;
        int pix = (e == 0) ? ec : (e == 1) ? 55 * 56 + ec : (e == 2) ? ec * 56 : ec * 56 + 55;
        size_t oi = ((size_t)(n * 128 + o)) * 3136 + pix;
        float old = out[oi];
        out[oi] = old - corr[k];
        sd -= corr[k];
        sq += corr[k] * corr[k] - 2.f * old * corr[k];
    }
    sd += __shfl_xor(sd, 1); sd += __shfl_xor(sd, 2);
    sq += __shfl_xor(sq, 1); sq += __shfl_xor(sq, 2);
    if (q == 0) {
        int slot = 896 + e * 32 + n;
        P[((size_t)slot * 2 + 0) * 128 + o] = sd;
        P[((size_t)slot * 2 + 1) * 128 + o] = sq;
    }
}

// ---------- corner add-back (fixes double-subtraction at 4 corners) ----------
__global__ __launch_bounds__(128) void corner_kernel(
    const float* __restrict__ x, const float* __restrict__ Uc,
    float* __restrict__ out, float* __restrict__ P) {
    __shared__ float xc[4][9][128];
    const int n = blockIdx.x, t = threadIdx.x;   // t = o
    for (int it = 0; it < 36; ++it) {
        int idx = it * 128 + t;                  // 4*9*128 = 4608 exact
        int c = idx % 128, p = (idx / 128) % 9, cr = idx / 1152;
        int di = p / 3, dj = p % 3;
        int hC = (cr >> 1) ? 55 : 0, wC = (cr & 1) ? 55 : 0;
        int khb = hC ? 2 : 0, kwb = wC ? 2 : 0;
        int hs = (hC + khb - 1 - (di - 1) + 56) % 56;
        int ws = (wC + kwb - 1 - (dj - 1) + 56) % 56;
        xc[cr][p][c] = x[(((size_t)n * 128 + c) * 56 + hs) * 56 + ws];
    }
    __syncthreads();
    float sd = 0.f, sq = 0.f;
#pragma unroll 1
    for (int cr = 0; cr < 4; ++cr) {
        float corr = 0.f;
#pragma unroll 1
        for (int p = 0; p < 9; ++p) {
            const float* uc = Uc + (((size_t)cr * 9 + p) * 128) * 128 + t;
            for (int c = 0; c < 128; ++c)
                corr = fmaf(uc[(size_t)c * 128], xc[cr][p][c], corr);
        }
        int hC = (cr >> 1) ? 55 : 0, wC = (cr & 1) ? 55 : 0;
        size_t oi = ((size_t)(n * 128 + t)) * 3136 + hC * 56 + wC;
        float old = out[oi];
        out[oi] = old + corr;
        sd += corr;
        sq += corr * corr + 2.f * old * corr;
    }
    P[((size_t)(1024 + n) * 2 + 0) * 128 + t] = sd;
    P[((size_t)(1024 + n) * 2 + 1) * 128 + t] = sq;
}

// ---------- finalize: reduce P -> scale/shift ----------
__global__ __launch_bounds__(256) void finalize_kernel(
    const float* __restrict__ P, const float* __restrict__ gamma,
    const float* __restrict__ beta, float* __restrict__ SS) {
    const int c = blockIdx.x, t = threadIdx.x;
    float s = 0.f, q = 0.f;
    for (int sl = t; sl < 1056; sl += 256) {
        s += P[((size_t)sl * 2 + 0) * 128 + c];
        q += P[((size_t)sl * 2 + 1) * 128 + c];
    }
    __shared__ float rs[256], rq[256];
    rs[t] = s; rq[t] = q;
    __syncthreads();
    for (int st = 128; st > 0; st >>= 1) {
        if (t < st) { rs[t] += rs[t + st]; rq[t] += rq[t + st]; }
        __syncthreads();
    }
    if (t == 0) {
        const float inv = 1.f / 100352.f;
        float mean = rs[0] * inv;
        float var  = rq[0] * inv - mean * mean;
        float sc = gamma[c] * rsqrtf(var + 1e-5f);
        SS[c] = sc;
        SS[128 + c] = beta[c] - mean * sc;
    }
}

__global__ __launch_bounds__(256) void bn_apply_kernel(
    float* __restrict__ out, const float* __restrict__ SS) {
    size_t idx = (size_t)blockIdx.x * 256 + threadIdx.x;   // 3,211,264 float4 exact
    int c = (int)((idx / 784) % 128);
    float sc = SS[c], sh = SS[128 + c];
    float4 v = ((float4*)out)[idx];
    v.x = fmaf(v.x, sc, sh);
    v.y = fmaf(v.y, sc, sh);
    v.z = fmaf(v.z, sc, sh);
    v.w = fmaf(v.w, sc, sh);
    ((float4*)out)[idx] = v;
}

extern "C" void kernel_launch(void* const* d_in, const int* in_sizes, int n_in,
                              void* d_out, int out_size, void* d_ws, size_t ws_size,
                              hipStream_t stream) {
    const float* x     = (const float*)d_in[0];
    const float* W     = (const float*)d_in[1];
    const float* gamma = (const float*)d_in[2];
    const float* beta  = (const float*)d_in[3];
    float* out = (float*)d_out;

    char* ws = (char*)d_ws;
    unsigned short* xb = (unsigned short*)ws;               // 25,690,112 B
    unsigned short* Ap = (unsigned short*)(ws + 25690112);  //    823,296 B (incl 4KB pad)
    float* U  = (float*)(ws + 26513408);                    //  3,932,160 B
    float* Uc = (float*)(ws + 30445568);                    //  2,359,296 B
    float* P  = (float*)(ws + 32804864);                    //  1,081,344 B
    float* SS = (float*)(ws + 33886208);                    //      1,024 B

    transpose_kernel<<<dim3(56, 32), 256, 0, stream>>>(x, xb);
    vpack_kernel<<<1600, 256, 0, stream>>>(W, Ap);
    ubuild_kernel<<<256, 256, 0, stream>>>(W, U);
    ucbuild_kernel<<<256, 256, 0, stream>>>(W, Uc);
    conv_mfma<<<dim3(7, 32), 512, 0, stream>>>(xb, Ap, out, P);
    border_kernel<<<dim3(2, 32, 2), 256, 0, stream>>>(x, U, out, P, 0);
    border_kernel<<<dim3(2, 32, 2), 256, 0, stream>>>(x, U, out, P, 2);
    corner_kernel<<<32, 128, 0, stream>>>(x, Uc, out, P);
    finalize_kernel<<<128, 256, 0, stream>>>(P, gamma, beta, SS);
    bn_apply_kernel<<<12544, 256, 0, stream>>>(out, SS);
}

// Round 6
// 395.948 us; speedup vs baseline: 7.5628x; 1.2778x over previous
//
#include <hip/hip_runtime.h>
#include <hip/hip_bf16.h>

// out = BN(sum_i conv3x3(roll(x, s_i), W_i)), x[32,128,56,56] fp32, W[8,128,128,3,3].
// Interior = circular 5x5 conv with collapsed weights V, computed as bf16 MFMA
// implicit GEMM (M=o 128, N=pixels, K=c*25taps=3200). Borders fixed exactly in
// fp32 via per-edge collapsed weights U + corner add-back Uc. BN stats fused
// into conv/border/corner epilogues as deterministic per-slot partials.

typedef __attribute__((ext_vector_type(8)))  short s16x8;   // 8 bf16 (4 VGPR)
typedef __attribute__((ext_vector_type(16))) float f32x16;  // MFMA 32x32 accum

__device__ __forceinline__ void gload16(const void* g, void* l) {
    __builtin_amdgcn_global_load_lds(
        (const __attribute__((address_space(1))) unsigned int*)g,
        (__attribute__((address_space(3))) unsigned int*)l, 16, 0, 0);
}

__device__ __forceinline__ unsigned short f2bf(float f) {
    __hip_bfloat16 h = __float2bfloat16(f);
    return *(unsigned short*)&h;
}

// ---------- prep 1: x[n][c][h][w] fp32 -> xb[n][h][w][c] bf16 ----------
__global__ __launch_bounds__(256) void transpose_kernel(
    const float* __restrict__ x, unsigned short* __restrict__ xb) {
    __shared__ float xt[128][57];
    const int h = blockIdx.x, n = blockIdx.y, t = threadIdx.x;
    for (int it = 0; it < 28; ++it) {
        int idx = it * 256 + t;                 // 7168 = 128c * 56w
        int c = idx / 56, w = idx % 56;
        xt[c][w] = x[(((size_t)n * 128 + c) * 56 + h) * 56 + w];
    }
    __syncthreads();
    for (int it = 0; it < 4; ++it) {
        int unit = it * 256 + t;                // 896 = 56w * 16cu
        if (unit < 896) {
            int w = unit >> 4, cu = unit & 15;
            unsigned short pk[8];
#pragma unroll
            for (int j = 0; j < 8; ++j) pk[j] = f2bf(xt[cu * 8 + j][w]);
            *(uint4*)(xb + ((((size_t)n * 56 + h) * 56 + w) * 128 + cu * 8)) = *(uint4*)pk;
        }
    }
}

// ---------- prep 2: W -> V(bf16) packed as 32x32x16 A-fragments ----------
// Ap layout: [chunk 8][tap 25][mo 4][lane 64][8 shorts]  (1KB per fragment)
__global__ __launch_bounds__(256) void vpack_kernel(
    const float* __restrict__ W, unsigned short* __restrict__ Ap) {
    int idx = blockIdx.x * 256 + threadIdx.x;   // 128*128*25 = 409600 exact
    int tap = idx % 25, oc = idx / 25, c = oc % 128, o = oc / 128;
    int a = tap / 5, b = tap % 5;
    const int dxs[8] = {-1, 0, 1, -1, 1, -1, 0, 1};
    const int dys[8] = {-1, -1, -1, 0, 0, 1, 1, 1};
    float s = 0.f;
#pragma unroll
    for (int i = 0; i < 8; ++i) {
        int kh = a - 1 + dxs[i];
        int kw = b - 1 + dys[i];
        if (kh >= 0 && kh < 3 && kw >= 0 && kw < 3)
            s += W[(((size_t)i * 128 + o) * 128 + c) * 9 + kh * 3 + kw];
    }
    int chunk = c >> 4, k = c & 15, ku = k >> 3, j = k & 7, mo = o >> 5;
    size_t off = ((((size_t)chunk * 25 + tap) * 4 + mo) * 64 + (ku * 32 + (o & 31))) * 8 + j;
    Ap[off] = f2bf(s);
}

// ---------- prep 3: per-edge collapsed border weights U[e][3r][5b][c][o] ----------
__global__ __launch_bounds__(256) void ubuild_kernel(
    const float* __restrict__ W, float* __restrict__ U) {
    int idx = blockIdx.x * 256 + threadIdx.x;   // 4*128*128 = 65536 exact
    int c = idx % 128, o = (idx / 128) % 128, e = idx / 16384;
    const int dxs[8] = {-1, 0, 1, -1, 1, -1, 0, 1};
    const int dys[8] = {-1, -1, -1, 0, 0, 1, 1, 1};
    float u[15];
#pragma unroll
    for (int k = 0; k < 15; ++k) u[k] = 0.f;
#pragma unroll
    for (int i = 0; i < 8; ++i) {
        if (e < 2) {
            int kh = (e == 0) ? 0 : 2;
            int hh = (e == 0) ? -1 : 56;
            int sr = (hh - dxs[i] + 56) % 56;
            int r = (e == 0) ? (sr == 54 ? 0 : sr == 55 ? 1 : 2)
                             : (sr == 55 ? 0 : sr == 0 ? 1 : 2);
#pragma unroll
            for (int kw = 0; kw < 3; ++kw) {
                int be = kw - 1 - dys[i] + 2;
                u[r * 5 + be] += W[(((size_t)i * 128 + o) * 128 + c) * 9 + kh * 3 + kw];
            }
        } else {
            int kw = (e == 2) ? 0 : 2;
            int ww = (e == 2) ? -1 : 56;
            int sc = (ww - dys[i] + 56) % 56;
            int r = (e == 2) ? (sc == 54 ? 0 : sc == 55 ? 1 : 2)
                             : (sc == 55 ? 0 : sc == 0 ? 1 : 2);
#pragma unroll
            for (int kh = 0; kh < 3; ++kh) {
                int al = kh - 1 - dxs[i] + 2;
                u[r * 5 + al] += W[(((size_t)i * 128 + o) * 128 + c) * 9 + kh * 3 + kw];
            }
        }
    }
#pragma unroll
    for (int k = 0; k < 15; ++k)
        U[(((size_t)e * 15 + k) * 128 + c) * 128 + o] = u[k];
}

// ---------- prep 4: corner add-back weights Uc[cr][9pos][c][o] ----------
__global__ __launch_bounds__(256) void ucbuild_kernel(
    const float* __restrict__ W, float* __restrict__ Uc) {
    int idx = blockIdx.x * 256 + threadIdx.x;   // 4*128*128
    int c = idx % 128, o = (idx / 128) % 128, cr = idx / 16384;
    int hC = (cr >> 1) ? 55 : 0, wC = (cr & 1) ? 55 : 0;
    int khb = hC ? 2 : 0, kwb = wC ? 2 : 0;
    const int dxs[8] = {-1, 0, 1, -1, 1, -1, 0, 1};
    const int dys[8] = {-1, -1, -1, 0, 0, 1, 1, 1};
    float v[9];
#pragma unroll
    for (int p = 0; p < 9; ++p) v[p] = 0.f;
#pragma unroll
    for (int i = 0; i < 8; ++i)
        v[(dxs[i] + 1) * 3 + (dys[i] + 1)] = W[(((size_t)i * 128 + o) * 128 + c) * 9 + khb * 3 + kwb];
#pragma unroll
    for (int p = 0; p < 9; ++p)
        Uc[(((size_t)cr * 9 + p) * 128 + c) * 128 + o] = v[p];
}

// ---------- main: circular 5x5 conv via MFMA implicit GEMM ----------
__global__ __launch_bounds__(512, 2) void conv_mfma(
    const unsigned short* __restrict__ xb, const unsigned short* __restrict__ Ap,
    float* __restrict__ out, float* __restrict__ P) {
    __shared__ __align__(16) unsigned short lds[69632];   // 139,264 B
    unsigned short* xs = lds;                    // 2048 units * 16B = 32,768 B
    unsigned short* As = lds + 16384;            // 6656 units * 16B = 106,496 B
    const int tile = blockIdx.x, n = blockIdx.y;
    const int p0 = tile * 512;
    const int t = threadIdx.x, wv = t >> 6, lane = t & 63;
    const int og = wv >> 2, pg = wv & 3;
    const int hstart = p0 / 56 - 2;

    int vB[4];
    bool fval[4];
#pragma unroll
    for (int nn = 0; nn < 4; ++nn) {
        int px = p0 + pg * 128 + nn * 32 + (lane & 31);
        fval[nn] = px < 3136;
        if (px > 3135) px = 3135;
        int h = px / 56, w = px % 56;
        vB[nn] = ((h - hstart - 2) * 60 + w) * 32 + (lane >> 5) * 16;   // bytes
    }
    f32x16 acc[2][4];
#pragma unroll
    for (int mm = 0; mm < 2; ++mm)
#pragma unroll
        for (int nn = 0; nn < 4; ++nn)
#pragma unroll
            for (int r = 0; r < 16; ++r) acc[mm][nn][r] = 0.f;

    const unsigned short* xbn = xb + (size_t)n * 401408;   // 56*56*128

#pragma unroll 1
    for (int ch = 0; ch < 8; ++ch) {
#pragma unroll
        for (int it = 0; it < 4; ++it) {
            int unit = it * 512 + t;            // 0..2047 (>=1800 = padding rows)
            int ph = unit >> 1, u = unit & 1;
            int r = ph / 60, wc2 = ph % 60;
            int gh = ((hstart + r) % 56 + 56) % 56;
            int gw = wc2 - 2;
            gw += (gw < 0) ? 56 : 0;
            gw -= (gw >= 56) ? 56 : 0;
            gload16(xbn + (gh * 56 + gw) * 128 + ch * 16 + u * 8,
                    (char*)xs + (size_t)(it * 512 + wv * 64) * 16);
        }
        const unsigned short* apc = Ap + (size_t)ch * 51200;
#pragma unroll
        for (int it = 0; it < 13; ++it) {
            int unit = it * 512 + t;            // 0..6655 (>=6400 = padding)
            gload16(apc + (size_t)unit * 8,
                    (char*)As + (size_t)(it * 512 + wv * 64) * 16);
        }
        __syncthreads();

#pragma unroll
        for (int tap = 0; tap < 25; ++tap) {
            const int toff = ((tap / 5) * 60 + (tap % 5)) * 32;
            s16x8 a0 = *(const s16x8*)((const char*)As + (size_t)(tap * 4 + og * 2 + 0) * 1024 + lane * 16);
            s16x8 a1 = *(const s16x8*)((const char*)As + (size_t)(tap * 4 + og * 2 + 1) * 1024 + lane * 16);
            s16x8 b0 = *(const s16x8*)((const char*)xs + vB[0] + toff);
            s16x8 b1 = *(const s16x8*)((const char*)xs + vB[1] + toff);
            s16x8 b2 = *(const s16x8*)((const char*)xs + vB[2] + toff);
            s16x8 b3 = *(const s16x8*)((const char*)xs + vB[3] + toff);
            acc[0][0] = __builtin_amdgcn_mfma_f32_32x32x16_bf16(a0, b0, acc[0][0], 0, 0, 0);
            acc[1][0] = __builtin_amdgcn_mfma_f32_32x32x16_bf16(a1, b0, acc[1][0], 0, 0, 0);
            acc[0][1] = __builtin_amdgcn_mfma_f32_32x32x16_bf16(a0, b1, acc[0][1], 0, 0, 0);
            acc[1][1] = __builtin_amdgcn_mfma_f32_32x32x16_bf16(a1, b1, acc[1][1], 0, 0, 0);
            acc[0][2] = __builtin_amdgcn_mfma_f32_32x32x16_bf16(a0, b2, acc[0][2], 0, 0, 0);
            acc[1][2] = __builtin_amdgcn_mfma_f32_32x32x16_bf16(a1, b2, acc[1][2], 0, 0, 0);
            acc[0][3] = __builtin_amdgcn_mfma_f32_32x32x16_bf16(a0, b3, acc[0][3], 0, 0, 0);
            acc[1][3] = __builtin_amdgcn_mfma_f32_32x32x16_bf16(a1, b3, acc[1][3], 0, 0, 0);
        }
        __syncthreads();
    }

    const int slot = (n * 7 + tile) * 4 + pg;
#pragma unroll
    for (int mm = 0; mm < 2; ++mm) {
#pragma unroll
        for (int r = 0; r < 16; ++r) {
            int o = og * 64 + mm * 32 + (r & 3) + ((lane >> 5) << 2) + ((r >> 2) << 3);
            float s = 0.f, q = 0.f;
#pragma unroll
            for (int nn = 0; nn < 4; ++nn) {
                if (fval[nn]) {
                    float v = acc[mm][nn][r];
                    size_t oi = ((size_t)(n * 128 + o)) * 3136 + (p0 + pg * 128 + nn * 32 + (lane & 31));
                    out[oi] = v;
                    s += v;
                    q = fmaf(v, v, q);
                }
            }
#pragma unroll
            for (int off = 1; off < 32; off <<= 1) {
                s += __shfl_xor(s, off);
                q += __shfl_xor(q, off);
            }
            if ((lane & 31) == 0) {
                P[((size_t)slot * 2 + 0) * 128 + o] = s;
                P[((size_t)slot * 2 + 1) * 128 + o] = q;
            }
        }
    }
}

// ---------- border: ONE launch, all 4 edges (disjoint writes) ----------
// grid (4 e, 32 n, 2 part): flat%8 = e + 4*(n&1) -> each XCD sees one U e-slice.
// 256 thr = 4 waves: wave = (oh, qh); o = oh*64 + lane (coalesced U reads);
// each thread: 14 px. e>=2 blocks skip the 2 corner px (deferred via Ccorn).
__global__ __launch_bounds__(256) void border_kernel(
    const float* __restrict__ x, const float* __restrict__ U,
    float* __restrict__ out, float* __restrict__ P, float* __restrict__ Ccorn) {
    __shared__ float xsb[3][128][32];
    __shared__ float psd[4][64], psq[4][64];
    const int e = blockIdx.x, n = blockIdx.y, part = blockIdx.z;
    const int t = threadIdx.x, lane = t & 63, wv = t >> 6;
    const int oh = wv >> 1, qh = wv & 1;
    int rows[3];
    if (e == 0 || e == 2) { rows[0] = 54; rows[1] = 55; rows[2] = 0; }
    else                  { rows[0] = 55; rows[1] = 0;  rows[2] = 1; }
    // stage x: 3 rows x 128 c x 32 cols (global col = part*28 + m - 2, circular)
    for (int it = 0; it < 48; ++it) {
        int idx = it * 256 + t;                 // 3*128*32 = 12288 exact
        int m = idx & 31, c = (idx >> 5) & 127, r = idx >> 12;
        int g = part * 28 + m - 2;
        g += (g < 0) ? 56 : 0;
        g -= (g >= 56) ? 56 : 0;
        xsb[r][c][m] = (e < 2) ? x[(((size_t)n * 128 + c) * 56 + rows[r]) * 56 + g]
                               : x[(((size_t)n * 128 + c) * 56 + g) * 56 + rows[r]];
    }
    __syncthreads();
    const int o = oh * 64 + lane;
    const int pxl = qh * 14;                    // local col base in staged tile
    float corr[14];
#pragma unroll
    for (int k = 0; k < 14; ++k) corr[k] = 0.f;
#pragma unroll 1
    for (int c = 0; c < 128; ++c) {
#pragma unroll
        for (int r = 0; r < 3; ++r) {
            float xl[18];
#pragma unroll
            for (int j = 0; j < 18; ++j) xl[j] = xsb[r][c][pxl + j];
#pragma unroll
            for (int be = 0; be < 5; ++be) {
                float u = U[(((size_t)e * 15 + r * 5 + be) * 128 + c) * 128 + o];
#pragma unroll
                for (int k = 0; k < 14; ++k) corr[k] = fmaf(u, xl[k + be], corr[k]);
            }
        }
    }
    float sd = 0.f, sq = 0.f;
#pragma unroll
    for (int k = 0; k < 14; ++k) {
        int p = part * 28 + qh * 14 + k;        // 0..55 along the edge
        bool isCorner = (e >= 2) && (p == 0 || p == 55);
        if (isCorner) {
            // cr: (0,0)=0 (e2,p0)  (0,55)=1 (e3,p0)  (55,0)=2 (e2,p55)  (55,55)=3 (e3,p55)
            int cr = ((p == 55) ? 2 : 0) + (e - 2);
            Ccorn[(size_t)cr * 4096 + n * 128 + o] = corr[k];
        } else {
            int pix = (e == 0) ? p : (e == 1) ? 55 * 56 + p : (e == 2) ? p * 56 : p * 56 + 55;
            size_t oi = ((size_t)(n * 128 + o)) * 3136 + pix;
            float old = out[oi];
            out[oi] = old - corr[k];
            sd -= corr[k];
            sq += corr[k] * corr[k] - 2.f * old * corr[k];
        }
    }
    psd[wv][lane] = sd; psq[wv][lane] = sq;
    __syncthreads();
    if (t < 128) {
        int oh2 = t >> 6, l2 = t & 63;
        int slot = 896 + (e * 32 + n) * 2 + part;
        P[((size_t)slot * 2 + 0) * 128 + oh2 * 64 + l2] = psd[oh2 * 2][l2] + psd[oh2 * 2 + 1][l2];
        P[((size_t)slot * 2 + 1) * 128 + oh2 * 64 + l2] = psq[oh2 * 2][l2] + psq[oh2 * 2 + 1][l2];
    }
}

// ---------- corner: apply (addback - deferred e>=2 corr) at 4 corners ----------
__global__ __launch_bounds__(128) void corner_kernel(
    const float* __restrict__ x, const float* __restrict__ Uc,
    float* __restrict__ out, float* __restrict__ P, const float* __restrict__ Ccorn) {
    __shared__ float xc[4][9][128];
    const int n = blockIdx.x, t = threadIdx.x;   // t = o
    for (int it = 0; it < 36; ++it) {
        int idx = it * 128 + t;                  // 4*9*128 = 4608 exact
        int c = idx % 128, p = (idx / 128) % 9, cr = idx / 1152;
        int di = p / 3, dj = p % 3;
        int hC = (cr >> 1) ? 55 : 0, wC = (cr & 1) ? 55 : 0;
        int khb = hC ? 2 : 0, kwb = wC ? 2 : 0;
        int hs = (hC + khb - 1 - (di - 1) + 56) % 56;
        int ws = (wC + kwb - 1 - (dj - 1) + 56) % 56;
        xc[cr][p][c] = x[(((size_t)n * 128 + c) * 56 + hs) * 56 + ws];
    }
    __syncthreads();
    float sd = 0.f, sq = 0.f;
#pragma unroll 1
    for (int cr = 0; cr < 4; ++cr) {
        float corr = 0.f;
#pragma unroll 1
        for (int p = 0; p < 9; ++p) {
            const float* uc = Uc + (((size_t)cr * 9 + p) * 128) * 128 + t;
            for (int c = 0; c < 128; ++c)
                corr = fmaf(uc[(size_t)c * 128], xc[cr][p][c], corr);
        }
        int hC = (cr >> 1) ? 55 : 0, wC = (cr & 1) ? 55 : 0;
        size_t oi = ((size_t)(n * 128 + t)) * 3136 + hC * 56 + wC;
        float dl = corr - Ccorn[(size_t)cr * 4096 + n * 128 + t];
        float old = out[oi];
        out[oi] = old + dl;
        sd += dl;
        sq += dl * dl + 2.f * old * dl;
    }
    P[((size_t)(1152 + n) * 2 + 0) * 128 + t] = sd;
    P[((size_t)(1152 + n) * 2 + 1) * 128 + t] = sq;
}

// ---------- finalize: reduce P -> scale/shift ----------
__global__ __launch_bounds__(256) void finalize_kernel(
    const float* __restrict__ P, const float* __restrict__ gamma,
    const float* __restrict__ beta, float* __restrict__ SS) {
    const int c = blockIdx.x, t = threadIdx.x;
    float s = 0.f, q = 0.f;
    for (int sl = t; sl < 1184; sl += 256) {
        s += P[((size_t)sl * 2 + 0) * 128 + c];
        q += P[((size_t)sl * 2 + 1) * 128 + c];
    }
    __shared__ float rs[256], rq[256];
    rs[t] = s; rq[t] = q;
    __syncthreads();
    for (int st = 128; st > 0; st >>= 1) {
        if (t < st) { rs[t] += rs[t + st]; rq[t] += rq[t + st]; }
        __syncthreads();
    }
    if (t == 0) {
        const float inv = 1.f / 100352.f;
        float mean = rs[0] * inv;
        float var  = rq[0] * inv - mean * mean;
        float sc = gamma[c] * rsqrtf(var + 1e-5f);
        SS[c] = sc;
        SS[128 + c] = beta[c] - mean * sc;
    }
}

__global__ __launch_bounds__(256) void bn_apply_kernel(
    float* __restrict__ out, const float* __restrict__ SS) {
    size_t idx = (size_t)blockIdx.x * 256 + threadIdx.x;   // 3,211,264 float4 exact
    int c = (int)((idx / 784) % 128);
    float sc = SS[c], sh = SS[128 + c];
    float4 v = ((float4*)out)[idx];
    v.x = fmaf(v.x, sc, sh);
    v.y = fmaf(v.y, sc, sh);
    v.z = fmaf(v.z, sc, sh);
    v.w = fmaf(v.w, sc, sh);
    ((float4*)out)[idx] = v;
}

extern "C" void kernel_launch(void* const* d_in, const int* in_sizes, int n_in,
                              void* d_out, int out_size, void* d_ws, size_t ws_size,
                              hipStream_t stream) {
    const float* x     = (const float*)d_in[0];
    const float* W     = (const float*)d_in[1];
    const float* gamma = (const float*)d_in[2];
    const float* beta  = (const float*)d_in[3];
    float* out = (float*)d_out;

    char* ws = (char*)d_ws;
    unsigned short* xb = (unsigned short*)ws;               // 25,690,112 B
    unsigned short* Ap = (unsigned short*)(ws + 25690112);  //    823,296 B
    float* U     = (float*)(ws + 26513408);                 //  3,932,160 B
    float* Uc    = (float*)(ws + 30445568);                 //  2,359,296 B
    float* P     = (float*)(ws + 32804864);                 //  1,212,416 B (1184 slots)
    float* SS    = (float*)(ws + 34017280);                 //      1,024 B
    float* Ccorn = (float*)(ws + 34018304);                 //     65,536 B

    transpose_kernel<<<dim3(56, 32), 256, 0, stream>>>(x, xb);
    vpack_kernel<<<1600, 256, 0, stream>>>(W, Ap);
    ubuild_kernel<<<256, 256, 0, stream>>>(W, U);
    ucbuild_kernel<<<256, 256, 0, stream>>>(W, Uc);
    conv_mfma<<<dim3(7, 32), 512, 0, stream>>>(xb, Ap, out, P);
    border_kernel<<<dim3(4, 32, 2), 256, 0, stream>>>(x, U, out, P, Ccorn);
    corner_kernel<<<32, 128, 0, stream>>>(x, Uc, out, P, Ccorn);
    finalize_kernel<<<128, 256, 0, stream>>>(P, gamma, beta, SS);
    bn_apply_kernel<<<12544, 256, 0, stream>>>(out, SS);
}